// Round 11
// baseline (255.862 us; speedup 1.0000x reference)
//
#include <hip/hip_runtime.h>
#include <math.h>

#define EPS 1e-5f
#define BSH 9              // bucket = dst >> 9 (512 nodes per bucket)
#define BSPAN 512
#define CHUNK 2048         // edges per block in hist/scatter
#define CAP 16384          // LDS staging capacity in k_build

typedef __attribute__((ext_vector_type(8))) short short8;
typedef __attribute__((ext_vector_type(4))) float f32x4;
typedef __attribute__((ext_vector_type(2))) float f32x2;

__device__ __forceinline__ short f2bf(float f) {
  union { float f; unsigned u; } v; v.f = f;
  unsigned r = v.u + 0x7fff + ((v.u >> 16) & 1);   // RNE
  return (short)(r >> 16);
}

// ------- merged prep: x->bf16+fp8 cast | bucket histogram | weight packing --
__global__ __launch_bounds__(256) void k_prep(
    const float* __restrict__ x, unsigned short* __restrict__ xbf,
    unsigned* __restrict__ xf8, long long n8,
    const int* __restrict__ ei, int* __restrict__ bcnt, int E, int n,
    int ncast, int nhist,
    const float* __restrict__ W1l, const float* __restrict__ W1r,
    short* __restrict__ wp1,
    const float* __restrict__ W2l, const float* __restrict__ W2r,
    short* __restrict__ wp2) {
  __shared__ int h[256];
  int b = blockIdx.x, tid = threadIdx.x;
  if (b < ncast) {
    long long i = (long long)b * 256 + tid;
    if (i < n8) {
      const float4* p = (const float4*)x + i * 2;
      float4 v0 = p[0], v1 = p[1];
      short8 o;
      o[0] = f2bf(v0.x); o[1] = f2bf(v0.y); o[2] = f2bf(v0.z); o[3] = f2bf(v0.w);
      o[4] = f2bf(v1.x); o[5] = f2bf(v1.y); o[6] = f2bf(v1.z); o[7] = f2bf(v1.w);
      ((short8*)xbf)[i] = o;
      unsigned lo = __builtin_amdgcn_cvt_pk_fp8_f32(v0.x, v0.y, 0u, false);
      lo = __builtin_amdgcn_cvt_pk_fp8_f32(v0.z, v0.w, lo, true);
      unsigned hi = __builtin_amdgcn_cvt_pk_fp8_f32(v1.x, v1.y, 0u, false);
      hi = __builtin_amdgcn_cvt_pk_fp8_f32(v1.z, v1.w, hi, true);
      ((uint2*)xf8)[i] = make_uint2(lo, hi);
    }
  } else if (b < ncast + nhist) {
    h[tid] = 0;
    __syncthreads();
    long long base = (long long)(b - ncast) * CHUNK;
#pragma unroll
    for (int i = 0; i < CHUNK / 256; ++i) {
      long long e = base + i * 256 + tid;
      if (e < E) {
        int d = ei[E + e];
        if ((unsigned)d < (unsigned)n) atomicAdd(&h[d >> BSH], 1);
      }
    }
    __syncthreads();
    if (h[tid]) atomicAdd(&bcnt[tid], h[tid]);
  } else if (b < ncast + nhist + 16) {
    int t = (b - ncast - nhist) * 256 + tid;   // 64 frags * 64 lanes
    int l = t & 63, f = t >> 6;
    int kt = f >> 3, ct = f & 7;
    int c = ct * 16 + (l & 15);
    int kb = kt * 32 + (l >> 4) * 8;
    short8 v;
#pragma unroll
    for (int j = 0; j < 8; ++j) {
      int k = kb + j;
      float w = (k < 128) ? W1l[k * 128 + c] : W1r[(k - 128) * 128 + c];
      v[j] = f2bf(w);
    }
    *(short8*)(wp1 + (size_t)t * 8) = v;
  } else {
    int t = (b - ncast - nhist - 16) * 256 + tid;  // 32 frags * 64 lanes
    int l = t & 63, f = t >> 6;
    int kt = f >> 3, ct = f & 7;
    int c = ct * 16 + (l & 15);
    int kb = kt * 32 + (l >> 4) * 8;
    short8 v;
#pragma unroll
    for (int j = 0; j < 8; ++j) {
      int k = kb + j;
      float w = (c < 64) ? W2l[k * 64 + c] : W2r[k * 64 + (c - 64)];
      v[j] = f2bf(w);
    }
    *(short8*)(wp2 + (size_t)t * 8) = v;
  }
}

// ---------------- CSR build pass 2: scan bucket counts ----------------------
__global__ __launch_bounds__(256) void k_bscan(
    const int* __restrict__ bcnt, int* __restrict__ bbase,
    int* __restrict__ bcur, int nbk) {
  __shared__ int s[256];
  int t = threadIdx.x;
  int v = (t < nbk) ? bcnt[t] : 0;
  s[t] = v;
  __syncthreads();
  for (int off = 1; off < 256; off <<= 1) {
    int xv = (t >= off) ? s[t - off] : 0;
    __syncthreads();
    s[t] += xv;
    __syncthreads();
  }
  int excl = s[t] - v;
  if (t < nbk) { bbase[t] = excl; bcur[t] = excl; }
}

// ---------------- CSR build pass 3: partition edges into buckets ------------
// epk[pos] = (dst_local << 18) | src   (n < 2^18)
__global__ __launch_bounds__(256) void k_scatter(
    const int* __restrict__ ei, int* __restrict__ bcur,
    unsigned* __restrict__ epk, int E, int n) {
  __shared__ int h[256];
  __shared__ int base[256];
  int tid = threadIdx.x;
  h[tid] = 0;
  __syncthreads();
  long long cbase = (long long)blockIdx.x * CHUNK;
  int src[CHUNK / 256], dl[CHUNK / 256], rk[CHUNK / 256], bk[CHUNK / 256];
#pragma unroll
  for (int i = 0; i < CHUNK / 256; ++i) {
    long long e = cbase + i * 256 + tid;
    bk[i] = -1;
    if (e < E) {
      int s = ei[e], d = ei[E + e];
      if ((unsigned)d < (unsigned)n) {
        bk[i] = d >> BSH; dl[i] = d & (BSPAN - 1); src[i] = s;
        rk[i] = atomicAdd(&h[bk[i]], 1);
      }
    }
  }
  __syncthreads();
  base[tid] = h[tid] ? atomicAdd(&bcur[tid], h[tid]) : 0;
  __syncthreads();
#pragma unroll
  for (int i = 0; i < CHUNK / 256; ++i) {
    if (bk[i] >= 0)
      epk[base[bk[i]] + rk[i]] = ((unsigned)dl[i] << 18) | (unsigned)src[i];
  }
}

// ------- CSR build pass 4: per-bucket local sort -> rowptr + ssrc -----------
__global__ __launch_bounds__(256) void k_build(
    const unsigned* __restrict__ epk, const int* __restrict__ bbase,
    const int* __restrict__ bcnt, int* __restrict__ rowptr,
    int* __restrict__ ssrc, int n, int nbk) {
  __shared__ int cnt[BSPAN];
  __shared__ int rp[BSPAN];
  __shared__ int cur[BSPAN];
  __shared__ int lsrc[CAP];
  int b = blockIdx.x, t = threadIdx.x;
  int segbase = bbase[b], segcnt = bcnt[b];
  int i0 = t, i1 = t + 256;
  cnt[i0] = 0; cnt[i1] = 0;
  __syncthreads();
  for (int i = t; i < segcnt; i += 256)
    atomicAdd(&cnt[epk[segbase + i] >> 18], 1);
  __syncthreads();
  rp[i0] = cnt[i0]; rp[i1] = cnt[i1];
  __syncthreads();
  for (int off = 1; off < BSPAN; off <<= 1) {
    int v0 = (i0 >= off) ? rp[i0 - off] : 0;
    int v1 = (i1 >= off) ? rp[i1 - off] : 0;
    __syncthreads();
    rp[i0] += v0; rp[i1] += v1;
    __syncthreads();
  }
  int e0 = rp[i0] - cnt[i0], e1 = rp[i1] - cnt[i1];
  cur[i0] = e0; cur[i1] = e1;
  int node0 = b * BSPAN;
  if (node0 + i0 < n) rowptr[node0 + i0] = segbase + e0;
  if (node0 + i1 < n) rowptr[node0 + i1] = segbase + e1;
  if (b == nbk - 1 && t == 0) rowptr[n] = segbase + segcnt;
  __syncthreads();
  if (segcnt <= CAP) {
    for (int i = t; i < segcnt; i += 256) {
      unsigned k = epk[segbase + i];
      int pos = atomicAdd(&cur[k >> 18], 1);
      lsrc[pos] = (int)(k & 0x3FFFFu);
    }
    __syncthreads();
    for (int i = t; i < segcnt; i += 256) ssrc[segbase + i] = lsrc[i];
  } else {
    for (int i = t; i < segcnt; i += 256) {
      unsigned k = epk[segbase + i];
      int pos = atomicAdd(&cur[k >> 18], 1);
      ssrc[segbase + pos] = (int)(k & 0x3FFFFu);
    }
  }
}

// --- gather-mean layer 1 (fp8): 1 edge per full wave, lane = 2 channels -----
// per edge: 1 idx load + 1 lshl_add voffset + 1 ushort load (128B/row
// coalesced) + 1 cvt_pk + 1 pk_add. No cross-lane reduction needed.
__global__ __launch_bounds__(256) void k_agg1(
    const int* __restrict__ rowptr, const int* __restrict__ ssrc,
    const unsigned short* __restrict__ x2, unsigned short* __restrict__ aggbf,
    int n) {
  int w = (blockIdx.x * 256 + threadIdx.x) >> 6;  // wave -> node
  if (w >= n) return;
  int l = threadIdx.x & 63;                       // lane -> channels 2l, 2l+1
  int beg = rowptr[w], end = rowptr[w + 1];
  f32x2 acc0 = {0.f, 0.f}, acc1 = {0.f, 0.f};
  int p = beg;
  for (; p + 7 < end; p += 8) {
    int s0 = ssrc[p + 0], s1 = ssrc[p + 1];
    int s2 = ssrc[p + 2], s3 = ssrc[p + 3];
    int s4 = ssrc[p + 4], s5 = ssrc[p + 5];
    int s6 = ssrc[p + 6], s7 = ssrc[p + 7];
    unsigned v0 = x2[(size_t)s0 * 64 + l];
    unsigned v1 = x2[(size_t)s1 * 64 + l];
    unsigned v2 = x2[(size_t)s2 * 64 + l];
    unsigned v3 = x2[(size_t)s3 * 64 + l];
    unsigned v4 = x2[(size_t)s4 * 64 + l];
    unsigned v5 = x2[(size_t)s5 * 64 + l];
    unsigned v6 = x2[(size_t)s6 * 64 + l];
    unsigned v7 = x2[(size_t)s7 * 64 + l];
    acc0 += __builtin_amdgcn_cvt_pk_f32_fp8(v0, false);
    acc1 += __builtin_amdgcn_cvt_pk_f32_fp8(v1, false);
    acc0 += __builtin_amdgcn_cvt_pk_f32_fp8(v2, false);
    acc1 += __builtin_amdgcn_cvt_pk_f32_fp8(v3, false);
    acc0 += __builtin_amdgcn_cvt_pk_f32_fp8(v4, false);
    acc1 += __builtin_amdgcn_cvt_pk_f32_fp8(v5, false);
    acc0 += __builtin_amdgcn_cvt_pk_f32_fp8(v6, false);
    acc1 += __builtin_amdgcn_cvt_pk_f32_fp8(v7, false);
  }
  for (; p < end; ++p) {
    unsigned v = x2[(size_t)ssrc[p] * 64 + l];
    acc0 += __builtin_amdgcn_cvt_pk_f32_fp8(v, false);
  }
  acc0 += acc1;
  float inv = 1.0f / fmaxf((float)(end - beg), 1.0f);
  unsigned o = ((unsigned)(unsigned short)f2bf(acc0[1] * inv) << 16)
             | (unsigned short)f2bf(acc0[0] * inv);
  ((unsigned*)aggbf)[(size_t)w * 64 + l] = o;
}

// ------------- layer 1 MFMA: h1 = relu(bn1([agg|x] @ Wcat1 + b1)) -----------
__global__ __launch_bounds__(256) void k_lin1(
    const unsigned short* __restrict__ xbf,
    const unsigned short* __restrict__ aggbf,
    const short* __restrict__ wp, const float* __restrict__ b,
    const float* __restrict__ g, const float* __restrict__ be,
    unsigned short* __restrict__ h1bf, int n) {
  __shared__ short As[64 * 256];  // 64 rows x 256 k, bf16, XOR-swizzled, 32 KB
  int tid = threadIdx.x;
  int row0 = blockIdx.x * 64;
#pragma unroll
  for (int it = 0; it < 8; ++it) {
    int slot = it * 256 + tid;     // 0..2047 16B chunks
    int r = slot >> 5;             // row 0..63
    int c16 = slot & 31;           // chunk (8 bf16); <16: agg half, else x half
    int gr = row0 + r;
    short8 o = {0, 0, 0, 0, 0, 0, 0, 0};
    if (gr < n) {
      const unsigned short* src = (c16 < 16)
          ? (aggbf + (size_t)gr * 128 + c16 * 8)
          : (xbf + (size_t)gr * 128 + (c16 - 16) * 8);
      o = *(const short8*)src;
    }
    int byte = r * 512 + ((c16 * 16) ^ ((r & 7) << 4));
    *(short8*)((char*)As + byte) = o;
  }
  __syncthreads();
  int w = tid >> 6, l = tid & 63;
  int rloc = w * 16 + (l & 15);
  f32x4 acc[8];
#pragma unroll
  for (int i = 0; i < 8; ++i) acc[i] = (f32x4){0.f, 0.f, 0.f, 0.f};
#pragma unroll
  for (int kt = 0; kt < 8; ++kt) {
    int abyte = rloc * 512 + ((kt * 64 + (l >> 4) * 16) ^ ((rloc & 7) << 4));
    short8 a = *(short8*)((char*)As + abyte);
#pragma unroll
    for (int ct = 0; ct < 8; ++ct) {
      short8 bf = *(const short8*)(wp + ((size_t)((kt * 8 + ct) * 64 + l)) * 8);
      acc[ct] = __builtin_amdgcn_mfma_f32_16x16x32_bf16(a, bf, acc[ct], 0, 0, 0);
    }
  }
  // epilogue: C/D layout col=lane&15, row=(lane>>4)*4+q
  int rbase = row0 + w * 16 + (l >> 4) * 4;
  int cb = l & 15;
#pragma unroll
  for (int ct = 0; ct < 8; ++ct) {
    int c = ct * 16 + cb;
    float sc = g[c] * (1.0f / sqrtf(1.0f + EPS));
    float bb = b[c], bt = be[c];
#pragma unroll
    for (int q = 0; q < 4; ++q) {
      int r = rbase + q;
      if (r < n) {
        float v = (acc[ct][q] + bb) * sc + bt;
        h1bf[(size_t)r * 128 + c] = (unsigned short)f2bf(fmaxf(v, 0.f));
      }
    }
  }
}

// --- layer 2 MFMA: [y(fp8) | pre(f32,d_out)] = h1 @ Wcat2 + [0|b2] ----------
__global__ __launch_bounds__(256) void k_lin2(
    const unsigned short* __restrict__ h1bf, const short* __restrict__ wp,
    const float* __restrict__ b2,
    unsigned char* __restrict__ yf8, float* __restrict__ pre, int n) {
  __shared__ short As[64 * 128];  // 16 KB
  int tid = threadIdx.x;
  int row0 = blockIdx.x * 64;
#pragma unroll
  for (int it = 0; it < 4; ++it) {
    int slot = it * 256 + tid;     // 0..1023
    int r = slot >> 4;             // row 0..63
    int c16 = slot & 15;
    int gr = row0 + r;
    short8 o = {0, 0, 0, 0, 0, 0, 0, 0};
    if (gr < n) o = *(const short8*)(h1bf + (size_t)gr * 128 + c16 * 8);
    int byte = r * 256 + ((c16 * 16) ^ ((r & 7) << 4));
    *(short8*)((char*)As + byte) = o;
  }
  __syncthreads();
  int w = tid >> 6, l = tid & 63;
  int rloc = w * 16 + (l & 15);
  f32x4 acc[8];
#pragma unroll
  for (int i = 0; i < 8; ++i) acc[i] = (f32x4){0.f, 0.f, 0.f, 0.f};
#pragma unroll
  for (int kt = 0; kt < 4; ++kt) {
    int abyte = rloc * 256 + ((kt * 64 + (l >> 4) * 16) ^ ((rloc & 7) << 4));
    short8 a = *(short8*)((char*)As + abyte);
#pragma unroll
    for (int ct = 0; ct < 8; ++ct) {
      short8 bf = *(const short8*)(wp + ((size_t)((kt * 8 + ct) * 64 + l)) * 8);
      acc[ct] = __builtin_amdgcn_mfma_f32_16x16x32_bf16(a, bf, acc[ct], 0, 0, 0);
    }
  }
  int rbase = row0 + w * 16 + (l >> 4) * 4;
  int cb = l & 15;
#pragma unroll
  for (int ct = 0; ct < 8; ++ct) {
    int c = ct * 16 + cb;
#pragma unroll
    for (int q = 0; q < 4; ++q) {
      int r = rbase + q;
      if (r < n) {
        if (c < 64) {
          unsigned pk = __builtin_amdgcn_cvt_pk_fp8_f32(
              acc[ct][q], acc[ct][q], 0u, false);
          yf8[(size_t)r * 64 + c] = (unsigned char)pk;
        } else {
          pre[(size_t)r * 64 + (c - 64)] = acc[ct][q] + b2[c - 64];
        }
      }
    }
  }
}

// --- gather-mean layer 2 + final BN+ReLU (fp8): 2 edges/wave (32-lane) ------
__global__ __launch_bounds__(256) void k_agg2(
    const int* __restrict__ rowptr, const int* __restrict__ ssrc,
    const unsigned short* __restrict__ y2, const float* __restrict__ g,
    const float* __restrict__ be, float* __restrict__ out, int n) {
  int w = (blockIdx.x * 256 + threadIdx.x) >> 6;  // wave -> node
  if (w >= n) return;
  int l = threadIdx.x & 63;
  int lh = l & 31, hh = l >> 5;   // lane -> ch 2lh,2lh+1; half-wave -> parity
  int beg = rowptr[w], end = rowptr[w + 1];
  f32x2 acc0 = {0.f, 0.f}, acc1 = {0.f, 0.f};
  int p = beg + hh;
  for (; p + 7 < end; p += 8) {
    int s0 = ssrc[p], s1 = ssrc[p + 2], s2 = ssrc[p + 4], s3 = ssrc[p + 6];
    unsigned v0 = y2[(size_t)s0 * 32 + lh];
    unsigned v1 = y2[(size_t)s1 * 32 + lh];
    unsigned v2 = y2[(size_t)s2 * 32 + lh];
    unsigned v3 = y2[(size_t)s3 * 32 + lh];
    acc0 += __builtin_amdgcn_cvt_pk_f32_fp8(v0, false);
    acc1 += __builtin_amdgcn_cvt_pk_f32_fp8(v1, false);
    acc0 += __builtin_amdgcn_cvt_pk_f32_fp8(v2, false);
    acc1 += __builtin_amdgcn_cvt_pk_f32_fp8(v3, false);
  }
  for (; p < end; p += 2) {
    unsigned v = y2[(size_t)ssrc[p] * 32 + lh];
    acc0 += __builtin_amdgcn_cvt_pk_f32_fp8(v, false);
  }
  acc0 += acc1;
  float a0 = acc0[0] + __shfl_xor(acc0[0], 32, 64);
  float a1 = acc0[1] + __shfl_xor(acc0[1], 32, 64);
  if (hh == 0) {
    float inv = 1.0f / fmaxf((float)(end - beg), 1.0f);
    float rr = 1.0f / sqrtf(1.0f + EPS);
    float2 gv = ((const float2*)g)[lh];
    float2 bv = ((const float2*)be)[lh];
    float2 po = ((const float2*)out)[(size_t)w * 32 + lh];
    float2 v;
    v.x = fmaxf((a0 * inv + po.x) * (gv.x * rr) + bv.x, 0.f);
    v.y = fmaxf((a1 * inv + po.y) * (gv.y * rr) + bv.y, 0.f);
    ((float2*)out)[(size_t)w * 32 + lh] = v;
  }
}

extern "C" void kernel_launch(void* const* d_in, const int* in_sizes, int n_in,
                              void* d_out, int out_size, void* d_ws, size_t ws_size,
                              hipStream_t stream) {
  const float* x   = (const float*)d_in[0];
  const int*   ei  = (const int*)d_in[1];
  const float* W1l = (const float*)d_in[2];
  const float* b1  = (const float*)d_in[3];
  const float* W1r = (const float*)d_in[4];
  const float* g1  = (const float*)d_in[5];
  const float* be1 = (const float*)d_in[6];
  const float* W2l = (const float*)d_in[7];
  const float* b2  = (const float*)d_in[8];
  const float* W2r = (const float*)d_in[9];
  const float* g2  = (const float*)d_in[10];
  const float* be2 = (const float*)d_in[11];
  float* out = (float*)d_out;

  int n = in_sizes[0] / 128;
  int E = in_sizes[1] / 2;
  int nbk = (n + BSPAN - 1) / BSPAN;   // 196 for n=100000 (fits 256)
  int nce = (int)(((long long)E + CHUNK - 1) / CHUNK);
  long long n8 = (long long)n * 16;    // 8-elem chunks in x
  int ncast = (int)((n8 + 255) / 256);

  // workspace carve-up (aligned to 256B)
  char* ws = (char*)d_ws;
  size_t o = 0;
  auto carve = [&](size_t bytes) {
    char* p = ws + o;
    o += (bytes + 255) & ~(size_t)255;
    return p;
  };
  int*      bcnt   = (int*)carve(256 * 4);
  int*      bbase  = (int*)carve(256 * 4);
  int*      bcur   = (int*)carve(256 * 4);
  unsigned* epk    = (unsigned*)carve((size_t)E * 4);
  int*      ssrc   = (int*)carve((size_t)E * 4);
  int*      rowptr = (int*)carve((size_t)(n + 1) * 4);
  short*    wp1    = (short*)carve((size_t)64 * 64 * 8 * 2);  // 64 KB
  short*    wp2    = (short*)carve((size_t)32 * 64 * 8 * 2);  // 32 KB
  unsigned short* xbf   = (unsigned short*)carve((size_t)n * 128 * 2);
  unsigned*       xf8   = (unsigned*)carve((size_t)n * 128);
  unsigned short* aggbf = (unsigned short*)carve((size_t)n * 128 * 2);
  unsigned short* h1bf  = (unsigned short*)carve((size_t)n * 128 * 2);
  unsigned char*  yf8   = (unsigned char*)carve((size_t)n * 64);

  hipMemsetAsync(bcnt, 0, 256 * 4, stream);

  // merged prep: cast + bucket histogram + weight packs (independent work)
  k_prep<<<ncast + nce + 24, 256, 0, stream>>>(
      x, xbf, xf8, n8, ei, bcnt, E, n, ncast, nce,
      W1l, W1r, wp1, W2l, W2r, wp2);
  k_bscan<<<1, 256, 0, stream>>>(bcnt, bbase, bcur, nbk);
  k_scatter<<<nce, 256, 0, stream>>>(ei, bcur, epk, E, n);
  k_build<<<nbk, 256, 0, stream>>>(epk, bbase, bcnt, rowptr, ssrc, n, nbk);

  {
    long long T = (long long)n * 64;
    k_agg1<<<(int)((T + 255) / 256), 256, 0, stream>>>(
        rowptr, ssrc, (const unsigned short*)xf8, aggbf, n);
  }
  k_lin1<<<(n + 63) / 64, 256, 0, stream>>>(xbf, aggbf, wp1, b1, g1, be1, h1bf, n);
  k_lin2<<<(n + 63) / 64, 256, 0, stream>>>(h1bf, wp2, b2, yf8, out, n);
  {
    long long T = (long long)n * 64;
    k_agg2<<<(int)((T + 255) / 256), 256, 0, stream>>>(
        rowptr, ssrc, (const unsigned short*)yf8, g2, be2, out, n);
  }
}

// Round 12
// 213.340 us; speedup vs baseline: 1.1993x; 1.1993x over previous
//
#include <hip/hip_runtime.h>
#include <math.h>

#define EPS 1e-5f
#define BSH 9              // bucket = dst >> 9 (512 nodes per bucket)
#define BSPAN 512
#define CHUNK 2048         // edges per block in hist/scatter
#define CAP 16384          // LDS staging capacity in k_build

typedef __attribute__((ext_vector_type(8))) short short8;
typedef __attribute__((ext_vector_type(4))) float f32x4;
typedef __attribute__((ext_vector_type(2))) float f32x2;

__device__ __forceinline__ short f2bf(float f) {
  union { float f; unsigned u; } v; v.f = f;
  unsigned r = v.u + 0x7fff + ((v.u >> 16) & 1);   // RNE
  return (short)(r >> 16);
}

// ------- merged prep: x->bf16+fp8 cast | bucket histogram | weight packing --
__global__ __launch_bounds__(256) void k_prep(
    const float* __restrict__ x, unsigned short* __restrict__ xbf,
    unsigned* __restrict__ xf8, long long n8,
    const int* __restrict__ ei, int* __restrict__ bcnt, int E, int n,
    int ncast, int nhist,
    const float* __restrict__ W1l, const float* __restrict__ W1r,
    short* __restrict__ wp1,
    const float* __restrict__ W2l, const float* __restrict__ W2r,
    short* __restrict__ wp2) {
  __shared__ int h[256];
  int b = blockIdx.x, tid = threadIdx.x;
  if (b < ncast) {
    long long i = (long long)b * 256 + tid;
    if (i < n8) {
      const float4* p = (const float4*)x + i * 2;
      float4 v0 = p[0], v1 = p[1];
      short8 o;
      o[0] = f2bf(v0.x); o[1] = f2bf(v0.y); o[2] = f2bf(v0.z); o[3] = f2bf(v0.w);
      o[4] = f2bf(v1.x); o[5] = f2bf(v1.y); o[6] = f2bf(v1.z); o[7] = f2bf(v1.w);
      ((short8*)xbf)[i] = o;
      unsigned lo = __builtin_amdgcn_cvt_pk_fp8_f32(v0.x, v0.y, 0u, false);
      lo = __builtin_amdgcn_cvt_pk_fp8_f32(v0.z, v0.w, lo, true);
      unsigned hi = __builtin_amdgcn_cvt_pk_fp8_f32(v1.x, v1.y, 0u, false);
      hi = __builtin_amdgcn_cvt_pk_fp8_f32(v1.z, v1.w, hi, true);
      ((uint2*)xf8)[i] = make_uint2(lo, hi);
    }
  } else if (b < ncast + nhist) {
    h[tid] = 0;
    __syncthreads();
    long long base = (long long)(b - ncast) * CHUNK;
#pragma unroll
    for (int i = 0; i < CHUNK / 256; ++i) {
      long long e = base + i * 256 + tid;
      if (e < E) {
        int d = ei[E + e];
        if ((unsigned)d < (unsigned)n) atomicAdd(&h[d >> BSH], 1);
      }
    }
    __syncthreads();
    if (h[tid]) atomicAdd(&bcnt[tid], h[tid]);
  } else if (b < ncast + nhist + 16) {
    int t = (b - ncast - nhist) * 256 + tid;   // 64 frags * 64 lanes
    int l = t & 63, f = t >> 6;
    int kt = f >> 3, ct = f & 7;
    int c = ct * 16 + (l & 15);
    int kb = kt * 32 + (l >> 4) * 8;
    short8 v;
#pragma unroll
    for (int j = 0; j < 8; ++j) {
      int k = kb + j;
      float w = (k < 128) ? W1l[k * 128 + c] : W1r[(k - 128) * 128 + c];
      v[j] = f2bf(w);
    }
    *(short8*)(wp1 + (size_t)t * 8) = v;
  } else {
    int t = (b - ncast - nhist - 16) * 256 + tid;  // 32 frags * 64 lanes
    int l = t & 63, f = t >> 6;
    int kt = f >> 3, ct = f & 7;
    int c = ct * 16 + (l & 15);
    int kb = kt * 32 + (l >> 4) * 8;
    short8 v;
#pragma unroll
    for (int j = 0; j < 8; ++j) {
      int k = kb + j;
      float w = (c < 64) ? W2l[k * 64 + c] : W2r[k * 64 + (c - 64)];
      v[j] = f2bf(w);
    }
    *(short8*)(wp2 + (size_t)t * 8) = v;
  }
}

// ---------------- CSR build pass 2: scan bucket counts ----------------------
__global__ __launch_bounds__(256) void k_bscan(
    const int* __restrict__ bcnt, int* __restrict__ bbase,
    int* __restrict__ bcur, int nbk) {
  __shared__ int s[256];
  int t = threadIdx.x;
  int v = (t < nbk) ? bcnt[t] : 0;
  s[t] = v;
  __syncthreads();
  for (int off = 1; off < 256; off <<= 1) {
    int xv = (t >= off) ? s[t - off] : 0;
    __syncthreads();
    s[t] += xv;
    __syncthreads();
  }
  int excl = s[t] - v;
  if (t < nbk) { bbase[t] = excl; bcur[t] = excl; }
}

// ---------------- CSR build pass 3: partition edges into buckets ------------
// epk[pos] = (dst_local << 18) | src   (n < 2^18)
__global__ __launch_bounds__(256) void k_scatter(
    const int* __restrict__ ei, int* __restrict__ bcur,
    unsigned* __restrict__ epk, int E, int n) {
  __shared__ int h[256];
  __shared__ int base[256];
  int tid = threadIdx.x;
  h[tid] = 0;
  __syncthreads();
  long long cbase = (long long)blockIdx.x * CHUNK;
  int src[CHUNK / 256], dl[CHUNK / 256], rk[CHUNK / 256], bk[CHUNK / 256];
#pragma unroll
  for (int i = 0; i < CHUNK / 256; ++i) {
    long long e = cbase + i * 256 + tid;
    bk[i] = -1;
    if (e < E) {
      int s = ei[e], d = ei[E + e];
      if ((unsigned)d < (unsigned)n) {
        bk[i] = d >> BSH; dl[i] = d & (BSPAN - 1); src[i] = s;
        rk[i] = atomicAdd(&h[bk[i]], 1);
      }
    }
  }
  __syncthreads();
  base[tid] = h[tid] ? atomicAdd(&bcur[tid], h[tid]) : 0;
  __syncthreads();
#pragma unroll
  for (int i = 0; i < CHUNK / 256; ++i) {
    if (bk[i] >= 0)
      epk[base[bk[i]] + rk[i]] = ((unsigned)dl[i] << 18) | (unsigned)src[i];
  }
}

// ------- CSR build pass 4: per-bucket local sort -> rowptr + ssrc -----------
__global__ __launch_bounds__(256) void k_build(
    const unsigned* __restrict__ epk, const int* __restrict__ bbase,
    const int* __restrict__ bcnt, int* __restrict__ rowptr,
    int* __restrict__ ssrc, int n, int nbk) {
  __shared__ int cnt[BSPAN];
  __shared__ int rp[BSPAN];
  __shared__ int cur[BSPAN];
  __shared__ int lsrc[CAP];
  int b = blockIdx.x, t = threadIdx.x;
  int segbase = bbase[b], segcnt = bcnt[b];
  int i0 = t, i1 = t + 256;
  cnt[i0] = 0; cnt[i1] = 0;
  __syncthreads();
  for (int i = t; i < segcnt; i += 256)
    atomicAdd(&cnt[epk[segbase + i] >> 18], 1);
  __syncthreads();
  rp[i0] = cnt[i0]; rp[i1] = cnt[i1];
  __syncthreads();
  for (int off = 1; off < BSPAN; off <<= 1) {
    int v0 = (i0 >= off) ? rp[i0 - off] : 0;
    int v1 = (i1 >= off) ? rp[i1 - off] : 0;
    __syncthreads();
    rp[i0] += v0; rp[i1] += v1;
    __syncthreads();
  }
  int e0 = rp[i0] - cnt[i0], e1 = rp[i1] - cnt[i1];
  cur[i0] = e0; cur[i1] = e1;
  int node0 = b * BSPAN;
  if (node0 + i0 < n) rowptr[node0 + i0] = segbase + e0;
  if (node0 + i1 < n) rowptr[node0 + i1] = segbase + e1;
  if (b == nbk - 1 && t == 0) rowptr[n] = segbase + segcnt;
  __syncthreads();
  if (segcnt <= CAP) {
    for (int i = t; i < segcnt; i += 256) {
      unsigned k = epk[segbase + i];
      int pos = atomicAdd(&cur[k >> 18], 1);
      lsrc[pos] = (int)(k & 0x3FFFFu);
    }
    __syncthreads();
    for (int i = t; i < segcnt; i += 256) ssrc[segbase + i] = lsrc[i];
  } else {
    for (int i = t; i < segcnt; i += 256) {
      unsigned k = epk[segbase + i];
      int pos = atomicAdd(&cur[k >> 18], 1);
      ssrc[segbase + pos] = (int)(k & 0x3FFFFu);
    }
  }
}

// --- gather-mean layer 1 (fp8): 4 edges/wave (16-lane x uint2), masked loop -
// single fully-predicated loop: 4 loads always in flight, no serial remainder
__global__ __launch_bounds__(256) void k_agg1(
    const int* __restrict__ rowptr, const int* __restrict__ ssrc,
    const unsigned* __restrict__ xf8, unsigned short* __restrict__ aggbf,
    int n) {
  int w = (blockIdx.x * 256 + threadIdx.x) >> 6;  // wave -> node
  if (w >= n) return;
  int l = threadIdx.x & 63;
  int q = l >> 4, ql = l & 15;    // quarter q -> edges p%4==q; ql -> ch 8ql..8ql+7
  int beg = rowptr[w], end = rowptr[w + 1];
  f32x2 a01 = {0.f, 0.f}, a23 = {0.f, 0.f}, a45 = {0.f, 0.f}, a67 = {0.f, 0.f};
  const uint2* xb2 = (const uint2*)xf8;   // row = 16 uint2 (128 fp8)
  int endm1 = end - 1;
  for (int p = beg + q; p < end; p += 16) {
    int i1 = p + 4, i2 = p + 8, i3 = p + 12;
    int j1 = min(i1, endm1), j2 = min(i2, endm1), j3 = min(i3, endm1);
    int s0 = ssrc[p], s1 = ssrc[j1], s2 = ssrc[j2], s3 = ssrc[j3];
    uint2 v0 = xb2[(size_t)s0 * 16 + ql];
    uint2 v1 = xb2[(size_t)s1 * 16 + ql];
    uint2 v2 = xb2[(size_t)s2 * 16 + ql];
    uint2 v3 = xb2[(size_t)s3 * 16 + ql];
    if (i1 > endm1) { v1.x = 0u; v1.y = 0u; }   // fp8 0x00 == 0.0f
    if (i2 > endm1) { v2.x = 0u; v2.y = 0u; }
    if (i3 > endm1) { v3.x = 0u; v3.y = 0u; }
    a01 += __builtin_amdgcn_cvt_pk_f32_fp8(v0.x, false);
    a23 += __builtin_amdgcn_cvt_pk_f32_fp8(v0.x, true);
    a45 += __builtin_amdgcn_cvt_pk_f32_fp8(v0.y, false);
    a67 += __builtin_amdgcn_cvt_pk_f32_fp8(v0.y, true);
    a01 += __builtin_amdgcn_cvt_pk_f32_fp8(v1.x, false);
    a23 += __builtin_amdgcn_cvt_pk_f32_fp8(v1.x, true);
    a45 += __builtin_amdgcn_cvt_pk_f32_fp8(v1.y, false);
    a67 += __builtin_amdgcn_cvt_pk_f32_fp8(v1.y, true);
    a01 += __builtin_amdgcn_cvt_pk_f32_fp8(v2.x, false);
    a23 += __builtin_amdgcn_cvt_pk_f32_fp8(v2.x, true);
    a45 += __builtin_amdgcn_cvt_pk_f32_fp8(v2.y, false);
    a67 += __builtin_amdgcn_cvt_pk_f32_fp8(v2.y, true);
    a01 += __builtin_amdgcn_cvt_pk_f32_fp8(v3.x, false);
    a23 += __builtin_amdgcn_cvt_pk_f32_fp8(v3.x, true);
    a45 += __builtin_amdgcn_cvt_pk_f32_fp8(v3.y, false);
    a67 += __builtin_amdgcn_cvt_pk_f32_fp8(v3.y, true);
  }
  float a[8] = {a01[0], a01[1], a23[0], a23[1], a45[0], a45[1], a67[0], a67[1]};
#pragma unroll
  for (int j = 0; j < 8; ++j) {
    a[j] += __shfl_xor(a[j], 16, 64);
    a[j] += __shfl_xor(a[j], 32, 64);
  }
  if (q == 0) {
    float inv = 1.0f / fmaxf((float)(end - beg), 1.0f);
    uint4 o;
    o.x = ((unsigned)(unsigned short)f2bf(a[1] * inv) << 16)
        | (unsigned short)f2bf(a[0] * inv);
    o.y = ((unsigned)(unsigned short)f2bf(a[3] * inv) << 16)
        | (unsigned short)f2bf(a[2] * inv);
    o.z = ((unsigned)(unsigned short)f2bf(a[5] * inv) << 16)
        | (unsigned short)f2bf(a[4] * inv);
    o.w = ((unsigned)(unsigned short)f2bf(a[7] * inv) << 16)
        | (unsigned short)f2bf(a[6] * inv);
    ((uint4*)aggbf)[(size_t)w * 16 + ql] = o;
  }
}

// ------------- layer 1 MFMA: h1 = relu(bn1([agg|x] @ Wcat1 + b1)) -----------
__global__ __launch_bounds__(256) void k_lin1(
    const unsigned short* __restrict__ xbf,
    const unsigned short* __restrict__ aggbf,
    const short* __restrict__ wp, const float* __restrict__ b,
    const float* __restrict__ g, const float* __restrict__ be,
    unsigned short* __restrict__ h1bf, int n) {
  __shared__ short As[64 * 256];  // 64 rows x 256 k, bf16, XOR-swizzled, 32 KB
  int tid = threadIdx.x;
  int row0 = blockIdx.x * 64;
#pragma unroll
  for (int it = 0; it < 8; ++it) {
    int slot = it * 256 + tid;     // 0..2047 16B chunks
    int r = slot >> 5;             // row 0..63
    int c16 = slot & 31;           // chunk (8 bf16); <16: agg half, else x half
    int gr = row0 + r;
    short8 o = {0, 0, 0, 0, 0, 0, 0, 0};
    if (gr < n) {
      const unsigned short* src = (c16 < 16)
          ? (aggbf + (size_t)gr * 128 + c16 * 8)
          : (xbf + (size_t)gr * 128 + (c16 - 16) * 8);
      o = *(const short8*)src;
    }
    int byte = r * 512 + ((c16 * 16) ^ ((r & 7) << 4));
    *(short8*)((char*)As + byte) = o;
  }
  __syncthreads();
  int w = tid >> 6, l = tid & 63;
  int rloc = w * 16 + (l & 15);
  f32x4 acc[8];
#pragma unroll
  for (int i = 0; i < 8; ++i) acc[i] = (f32x4){0.f, 0.f, 0.f, 0.f};
#pragma unroll
  for (int kt = 0; kt < 8; ++kt) {
    int abyte = rloc * 512 + ((kt * 64 + (l >> 4) * 16) ^ ((rloc & 7) << 4));
    short8 a = *(short8*)((char*)As + abyte);
#pragma unroll
    for (int ct = 0; ct < 8; ++ct) {
      short8 bf = *(const short8*)(wp + ((size_t)((kt * 8 + ct) * 64 + l)) * 8);
      acc[ct] = __builtin_amdgcn_mfma_f32_16x16x32_bf16(a, bf, acc[ct], 0, 0, 0);
    }
  }
  // epilogue: C/D layout col=lane&15, row=(lane>>4)*4+q
  int rbase = row0 + w * 16 + (l >> 4) * 4;
  int cb = l & 15;
#pragma unroll
  for (int ct = 0; ct < 8; ++ct) {
    int c = ct * 16 + cb;
    float sc = g[c] * (1.0f / sqrtf(1.0f + EPS));
    float bb = b[c], bt = be[c];
#pragma unroll
    for (int q = 0; q < 4; ++q) {
      int r = rbase + q;
      if (r < n) {
        float v = (acc[ct][q] + bb) * sc + bt;
        h1bf[(size_t)r * 128 + c] = (unsigned short)f2bf(fmaxf(v, 0.f));
      }
    }
  }
}

// --- layer 2 MFMA: [y(fp8) | pre(f32,d_out)] = h1 @ Wcat2 + [0|b2] ----------
__global__ __launch_bounds__(256) void k_lin2(
    const unsigned short* __restrict__ h1bf, const short* __restrict__ wp,
    const float* __restrict__ b2,
    unsigned char* __restrict__ yf8, float* __restrict__ pre, int n) {
  __shared__ short As[64 * 128];  // 16 KB
  int tid = threadIdx.x;
  int row0 = blockIdx.x * 64;
#pragma unroll
  for (int it = 0; it < 4; ++it) {
    int slot = it * 256 + tid;     // 0..1023
    int r = slot >> 4;             // row 0..63
    int c16 = slot & 15;
    int gr = row0 + r;
    short8 o = {0, 0, 0, 0, 0, 0, 0, 0};
    if (gr < n) o = *(const short8*)(h1bf + (size_t)gr * 128 + c16 * 8);
    int byte = r * 256 + ((c16 * 16) ^ ((r & 7) << 4));
    *(short8*)((char*)As + byte) = o;
  }
  __syncthreads();
  int w = tid >> 6, l = tid & 63;
  int rloc = w * 16 + (l & 15);
  f32x4 acc[8];
#pragma unroll
  for (int i = 0; i < 8; ++i) acc[i] = (f32x4){0.f, 0.f, 0.f, 0.f};
#pragma unroll
  for (int kt = 0; kt < 4; ++kt) {
    int abyte = rloc * 256 + ((kt * 64 + (l >> 4) * 16) ^ ((rloc & 7) << 4));
    short8 a = *(short8*)((char*)As + abyte);
#pragma unroll
    for (int ct = 0; ct < 8; ++ct) {
      short8 bf = *(const short8*)(wp + ((size_t)((kt * 8 + ct) * 64 + l)) * 8);
      acc[ct] = __builtin_amdgcn_mfma_f32_16x16x32_bf16(a, bf, acc[ct], 0, 0, 0);
    }
  }
  int rbase = row0 + w * 16 + (l >> 4) * 4;
  int cb = l & 15;
#pragma unroll
  for (int ct = 0; ct < 8; ++ct) {
    int c = ct * 16 + cb;
#pragma unroll
    for (int q = 0; q < 4; ++q) {
      int r = rbase + q;
      if (r < n) {
        if (c < 64) {
          unsigned pk = __builtin_amdgcn_cvt_pk_fp8_f32(
              acc[ct][q], acc[ct][q], 0u, false);
          yf8[(size_t)r * 64 + c] = (unsigned char)pk;
        } else {
          pre[(size_t)r * 64 + (c - 64)] = acc[ct][q] + b2[c - 64];
        }
      }
    }
  }
}

// --- gather-mean layer 2 + final BN+ReLU (fp8): 4 edges/wave, masked loop ---
__global__ __launch_bounds__(256) void k_agg2(
    const int* __restrict__ rowptr, const int* __restrict__ ssrc,
    const unsigned* __restrict__ yf8, const float* __restrict__ g,
    const float* __restrict__ be, float* __restrict__ out, int n) {
  int w = (blockIdx.x * 256 + threadIdx.x) >> 6;  // wave -> node
  if (w >= n) return;
  int l = threadIdx.x & 63;
  int q = l >> 4, ql = l & 15;    // quarter q -> edges p%4==q; ql -> ch 4ql..4ql+3
  int beg = rowptr[w], end = rowptr[w + 1];
  f32x2 a01 = {0.f, 0.f}, a23 = {0.f, 0.f};
  int endm1 = end - 1;
  for (int p = beg + q; p < end; p += 16) {
    int i1 = p + 4, i2 = p + 8, i3 = p + 12;
    int j1 = min(i1, endm1), j2 = min(i2, endm1), j3 = min(i3, endm1);
    int s0 = ssrc[p], s1 = ssrc[j1], s2 = ssrc[j2], s3 = ssrc[j3];
    unsigned v0 = yf8[(size_t)s0 * 16 + ql];
    unsigned v1 = yf8[(size_t)s1 * 16 + ql];
    unsigned v2 = yf8[(size_t)s2 * 16 + ql];
    unsigned v3 = yf8[(size_t)s3 * 16 + ql];
    if (i1 > endm1) v1 = 0u;
    if (i2 > endm1) v2 = 0u;
    if (i3 > endm1) v3 = 0u;
    a01 += __builtin_amdgcn_cvt_pk_f32_fp8(v0, false);
    a23 += __builtin_amdgcn_cvt_pk_f32_fp8(v0, true);
    a01 += __builtin_amdgcn_cvt_pk_f32_fp8(v1, false);
    a23 += __builtin_amdgcn_cvt_pk_f32_fp8(v1, true);
    a01 += __builtin_amdgcn_cvt_pk_f32_fp8(v2, false);
    a23 += __builtin_amdgcn_cvt_pk_f32_fp8(v2, true);
    a01 += __builtin_amdgcn_cvt_pk_f32_fp8(v3, false);
    a23 += __builtin_amdgcn_cvt_pk_f32_fp8(v3, true);
  }
  float a0 = a01[0], a1 = a01[1], a2 = a23[0], a3 = a23[1];
  a0 += __shfl_xor(a0, 16, 64); a0 += __shfl_xor(a0, 32, 64);
  a1 += __shfl_xor(a1, 16, 64); a1 += __shfl_xor(a1, 32, 64);
  a2 += __shfl_xor(a2, 16, 64); a2 += __shfl_xor(a2, 32, 64);
  a3 += __shfl_xor(a3, 16, 64); a3 += __shfl_xor(a3, 32, 64);
  if (q == 0) {
    float inv = 1.0f / fmaxf((float)(end - beg), 1.0f);
    float rr = 1.0f / sqrtf(1.0f + EPS);
    float4 gv = ((const float4*)g)[ql];
    float4 bv = ((const float4*)be)[ql];
    float4 po = ((const float4*)out)[(size_t)w * 16 + ql];
    float4 v;
    v.x = fmaxf((a0 * inv + po.x) * (gv.x * rr) + bv.x, 0.f);
    v.y = fmaxf((a1 * inv + po.y) * (gv.y * rr) + bv.y, 0.f);
    v.z = fmaxf((a2 * inv + po.z) * (gv.z * rr) + bv.z, 0.f);
    v.w = fmaxf((a3 * inv + po.w) * (gv.w * rr) + bv.w, 0.f);
    ((float4*)out)[(size_t)w * 16 + ql] = v;
  }
}

extern "C" void kernel_launch(void* const* d_in, const int* in_sizes, int n_in,
                              void* d_out, int out_size, void* d_ws, size_t ws_size,
                              hipStream_t stream) {
  const float* x   = (const float*)d_in[0];
  const int*   ei  = (const int*)d_in[1];
  const float* W1l = (const float*)d_in[2];
  const float* b1  = (const float*)d_in[3];
  const float* W1r = (const float*)d_in[4];
  const float* g1  = (const float*)d_in[5];
  const float* be1 = (const float*)d_in[6];
  const float* W2l = (const float*)d_in[7];
  const float* b2  = (const float*)d_in[8];
  const float* W2r = (const float*)d_in[9];
  const float* g2  = (const float*)d_in[10];
  const float* be2 = (const float*)d_in[11];
  float* out = (float*)d_out;

  int n = in_sizes[0] / 128;
  int E = in_sizes[1] / 2;
  int nbk = (n + BSPAN - 1) / BSPAN;   // 196 for n=100000 (fits 256)
  int nce = (int)(((long long)E + CHUNK - 1) / CHUNK);
  long long n8 = (long long)n * 16;    // 8-elem chunks in x
  int ncast = (int)((n8 + 255) / 256);

  // workspace carve-up (aligned to 256B)
  char* ws = (char*)d_ws;
  size_t o = 0;
  auto carve = [&](size_t bytes) {
    char* p = ws + o;
    o += (bytes + 255) & ~(size_t)255;
    return p;
  };
  int*      bcnt   = (int*)carve(256 * 4);
  int*      bbase  = (int*)carve(256 * 4);
  int*      bcur   = (int*)carve(256 * 4);
  unsigned* epk    = (unsigned*)carve((size_t)E * 4);
  int*      ssrc   = (int*)carve((size_t)E * 4);
  int*      rowptr = (int*)carve((size_t)(n + 1) * 4);
  short*    wp1    = (short*)carve((size_t)64 * 64 * 8 * 2);  // 64 KB
  short*    wp2    = (short*)carve((size_t)32 * 64 * 8 * 2);  // 32 KB
  unsigned short* xbf   = (unsigned short*)carve((size_t)n * 128 * 2);
  unsigned*       xf8   = (unsigned*)carve((size_t)n * 128);
  unsigned short* aggbf = (unsigned short*)carve((size_t)n * 128 * 2);
  unsigned short* h1bf  = (unsigned short*)carve((size_t)n * 128 * 2);
  unsigned char*  yf8   = (unsigned char*)carve((size_t)n * 64);

  hipMemsetAsync(bcnt, 0, 256 * 4, stream);

  // merged prep: cast + bucket histogram + weight packs (independent work)
  k_prep<<<ncast + nce + 24, 256, 0, stream>>>(
      x, xbf, xf8, n8, ei, bcnt, E, n, ncast, nce,
      W1l, W1r, wp1, W2l, W2r, wp2);
  k_bscan<<<1, 256, 0, stream>>>(bcnt, bbase, bcur, nbk);
  k_scatter<<<nce, 256, 0, stream>>>(ei, bcur, epk, E, n);
  k_build<<<nbk, 256, 0, stream>>>(epk, bbase, bcnt, rowptr, ssrc, n, nbk);

  {
    long long T = (long long)n * 64;
    k_agg1<<<(int)((T + 255) / 256), 256, 0, stream>>>(
        rowptr, ssrc, xf8, aggbf, n);
  }
  k_lin1<<<(n + 63) / 64, 256, 0, stream>>>(xbf, aggbf, wp1, b1, g1, be1, h1bf, n);
  k_lin2<<<(n + 63) / 64, 256, 0, stream>>>(h1bf, wp2, b2, yf8, out, n);
  {
    long long T = (long long)n * 64;
    k_agg2<<<(int)((T + 255) / 256), 256, 0, stream>>>(
        rowptr, ssrc, (const unsigned*)yf8, g2, be2, out, n);
  }
}